// Round 12
// baseline (350.457 us; speedup 1.0000x reference)
//
#include <hip/hip_runtime.h>
#include <hip/hip_bf16.h>

// GAT 2-layer forward. N=50000, E=800000 (+N self loops), IN=256,
// layer1: 8 heads x 32 (concat -> 256), relu, layer2: 256 -> 64, 1 head.
// Round 12: (a) nontemporal bucket/output streams in gathers so the
// XCD-L2-resident h slab stops being evicted (R11: FETCH 154MB = re-fetch
// bound); (b) att1/att2 fused into GEMM epilogues via 16-lane shfl_xor
// reduction over fp32 accumulators. 6 kernels total.

#define HEADS 8
#define HID 32
#define F1 256   // IN and layer-1 output width (8*32)
#define F2 64    // layer-2 output width
#define NEG_SLOPE 0.2f
#define CAP 128  // bucket slots per node (max in-degree ~45 for Poisson(16))

typedef __attribute__((ext_vector_type(8))) short bf16x8;
typedef __attribute__((ext_vector_type(4))) float f32x4;
typedef __attribute__((ext_vector_type(8))) unsigned short u16x8;
typedef __attribute__((ext_vector_type(4))) unsigned short u16x4;
typedef __attribute__((ext_vector_type(4))) int i32x4;

__device__ __forceinline__ unsigned short f2b(float f) {
    union { float f; unsigned int i; } x; x.f = f;
    unsigned int r = x.i + 0x7fffu + ((x.i >> 16) & 1u);  // RNE
    return (unsigned short)(r >> 16);
}
__device__ __forceinline__ float b2f(unsigned short u) {
    union { unsigned int i; float f; } x; x.i = ((unsigned int)u) << 16;
    return x.f;
}
__device__ __forceinline__ float leaky(float v) {
    return v > 0.f ? v : NEG_SLOPE * v;
}

// ---------------- setup: W1T, W2T casts + cursor zero -------------------
__global__ void setup_kernel(const float* __restrict__ W1,
                             const float* __restrict__ W2,
                             unsigned short* __restrict__ W1T,
                             unsigned short* __restrict__ W2T,
                             int* __restrict__ cursor, int Nn) {
    const int i = blockIdx.x * 256 + threadIdx.x;
    if (i < F1 * F1) {                       // W1 [F1,F1] -> W1T [n][k]
        const int k = i >> 8, n = i & (F1 - 1);
        W1T[(size_t)n * F1 + k] = f2b(W1[i]);
    } else if (i < F1 * F1 + F1 * F2) {      // W2 [F1,F2] -> W2T [n][k]
        const int j = i - F1 * F1;
        const int k = j >> 6, n = j & (F2 - 1);
        W2T[(size_t)n * F1 + k] = f2b(W2[j]);
    } else if (i < F1 * F1 + F1 * F2 + Nn) {
        cursor[i - F1 * F1 - F1 * F2] = 0;
    }
}

// ---------------- bucket scatter (by dst), nt writes --------------------
__global__ void scatter_kernel(const int* __restrict__ ei, int E,
                               int* __restrict__ cursor,
                               int* __restrict__ bucket) {
    const int e = blockIdx.x * blockDim.x + threadIdx.x;
    if (e >= E) return;
    const int d = ei[E + e];
    const int pos = atomicAdd(&cursor[d], 1);
    if (pos < CAP)
        __builtin_nontemporal_store(ei[e], &bucket[(size_t)d * CAP + pos]);
}

// ---------------- MFMA GEMM: C[M,N] = A[M,K] @ BT[N,K]^T ----------------
// OUT_MODE: 1 = bf16 node-major, 2 = bf16 head-major [col/32][row][32]
// FUSE: 0 none, 1 = multi-head att (layer 1), 2 = single-head-64 (layer 2)
template<int BN, bool A_FP32, int OUT_MODE, int FUSE>
__global__ __launch_bounds__(256) void mfma_gemm(
        const void* __restrict__ A,
        const unsigned short* __restrict__ BT,
        void* __restrict__ C,
        const float* __restrict__ attS, const float* __restrict__ attD,
        float* __restrict__ aS, float* __restrict__ aD,
        int M, int N, int K) {
    constexpr int BM = 128, BK = 32;
    __shared__ unsigned short As[BM * BK];
    __shared__ unsigned short Bs[BN * BK];
    const int tid = threadIdx.x;
    const int wave = tid >> 6, lane = tid & 63;
    const int quad = lane >> 4, l16 = lane & 15;
    const int brow = blockIdx.x * BM;
    const int bcol = blockIdx.y * BN;

    constexpr int MI = (BN == 128) ? 4 : 2;
    constexpr int NJ = 4;
    const int wm = (BN == 128) ? (wave & 1) * 64 : wave * 32;
    const int wn = (BN == 128) ? (wave >> 1) * 64 : 0;

    f32x4 acc[MI][NJ] = {};

    for (int k0 = 0; k0 < K; k0 += BK) {
#pragma unroll
        for (int it = 0; it < (BM * BK) / (256 * 8); ++it) {
            const int idx = it * 256 + tid;
            const int r = idx >> 2;
            const int kk = (idx & 3) * 8;
            const int gr = brow + r;
            if (A_FP32) {
                const float* Af = (const float*)A;
                float4 a0 = make_float4(0.f, 0.f, 0.f, 0.f);
                float4 a1 = make_float4(0.f, 0.f, 0.f, 0.f);
                if (gr < M) {
                    a0 = *(const float4*)&Af[(size_t)gr * K + k0 + kk];
                    a1 = *(const float4*)&Af[(size_t)gr * K + k0 + kk + 4];
                }
                ushort4 lo, hi;
                lo.x = f2b(a0.x); lo.y = f2b(a0.y); lo.z = f2b(a0.z); lo.w = f2b(a0.w);
                hi.x = f2b(a1.x); hi.y = f2b(a1.y); hi.z = f2b(a1.z); hi.w = f2b(a1.w);
                *(ushort4*)&As[r * BK + kk] = lo;
                *(ushort4*)&As[r * BK + kk + 4] = hi;
            } else {
                const unsigned short* Ab = (const unsigned short*)A;
                uint4 v = make_uint4(0u, 0u, 0u, 0u);
                if (gr < M) v = *(const uint4*)&Ab[(size_t)gr * K + k0 + kk];
                *(uint4*)&As[r * BK + kk] = v;
            }
        }
#pragma unroll
        for (int it = 0; it < (BN * BK) / (256 * 8); ++it) {
            const int idx = it * 256 + tid;
            const int r = idx >> 2;
            const int kk = (idx & 3) * 8;
            const uint4 v = *(const uint4*)&BT[(size_t)(bcol + r) * K + k0 + kk];
            *(uint4*)&Bs[r * BK + kk] = v;
        }
        __syncthreads();
        bf16x8 af[MI], bfr[NJ];
#pragma unroll
        for (int i = 0; i < MI; ++i)
            af[i] = *(const bf16x8*)&As[(wm + i * 16 + l16) * BK + quad * 8];
#pragma unroll
        for (int j = 0; j < NJ; ++j)
            bfr[j] = *(const bf16x8*)&Bs[(wn + j * 16 + l16) * BK + quad * 8];
#pragma unroll
        for (int i = 0; i < MI; ++i)
#pragma unroll
            for (int j = 0; j < NJ; ++j)
                acc[i][j] = __builtin_amdgcn_mfma_f32_16x16x32_bf16(
                    af[i], bfr[j], acc[i][j], 0, 0, 0);
        __syncthreads();
    }
    // ---- C store ----
#pragma unroll
    for (int i = 0; i < MI; ++i) {
#pragma unroll
        for (int r = 0; r < 4; ++r) {
            const int row = brow + wm + i * 16 + quad * 4 + r;
            if (row >= M) continue;
#pragma unroll
            for (int j = 0; j < NJ; ++j) {
                const int col = bcol + wn + j * 16 + l16;
                const float v = acc[i][j][r];
                if (OUT_MODE == 1) {
                    ((unsigned short*)C)[(size_t)row * N + col] = f2b(v);
                } else {
                    ((unsigned short*)C)[((size_t)(col >> 5) * M + row) * HID
                                         + (col & 31)] = f2b(v);
                }
            }
        }
    }
    // ---- fused attention coefficients ----
    if (FUSE == 1) {
        // wave covers 2 heads: head0 (j=0,1), head0+1 (j=2,3)
        const int head0 = (bcol + wn) >> 5;
        const float aS0 = attS[head0 * 32 + l16];
        const float aS1 = attS[head0 * 32 + 16 + l16];
        const float aS2 = attS[(head0 + 1) * 32 + l16];
        const float aS3 = attS[(head0 + 1) * 32 + 16 + l16];
        const float aD0 = attD[head0 * 32 + l16];
        const float aD1 = attD[head0 * 32 + 16 + l16];
        const float aD2 = attD[(head0 + 1) * 32 + l16];
        const float aD3 = attD[(head0 + 1) * 32 + 16 + l16];
#pragma unroll
        for (int i = 0; i < MI; ++i) {
#pragma unroll
            for (int r = 0; r < 4; ++r) {
                float s0 = acc[i][0][r] * aS0 + acc[i][1][r] * aS1;
                float s1 = acc[i][2][r] * aS2 + acc[i][3][r] * aS3;
                float d0 = acc[i][0][r] * aD0 + acc[i][1][r] * aD1;
                float d1 = acc[i][2][r] * aD2 + acc[i][3][r] * aD3;
#pragma unroll
                for (int off = 1; off < 16; off <<= 1) {
                    s0 += __shfl_xor(s0, off, 64);
                    s1 += __shfl_xor(s1, off, 64);
                    d0 += __shfl_xor(d0, off, 64);
                    d1 += __shfl_xor(d1, off, 64);
                }
                const int row = brow + wm + i * 16 + quad * 4 + r;
                if (l16 == 0 && row < M) {
                    aS[(size_t)head0 * M + row] = s0;
                    aS[(size_t)(head0 + 1) * M + row] = s1;
                    aD[(size_t)head0 * M + row] = d0;
                    aD[(size_t)(head0 + 1) * M + row] = d1;
                }
            }
        }
    } else if (FUSE == 2) {
        // single head, cols 0..63 (BN==64, wn==0)
        const float aSj0 = attS[l16],      aDj0 = attD[l16];
        const float aSj1 = attS[16 + l16], aDj1 = attD[16 + l16];
        const float aSj2 = attS[32 + l16], aDj2 = attD[32 + l16];
        const float aSj3 = attS[48 + l16], aDj3 = attD[48 + l16];
#pragma unroll
        for (int i = 0; i < MI; ++i) {
#pragma unroll
            for (int r = 0; r < 4; ++r) {
                float s = acc[i][0][r] * aSj0 + acc[i][1][r] * aSj1
                        + acc[i][2][r] * aSj2 + acc[i][3][r] * aSj3;
                float d = acc[i][0][r] * aDj0 + acc[i][1][r] * aDj1
                        + acc[i][2][r] * aDj2 + acc[i][3][r] * aDj3;
#pragma unroll
                for (int off = 1; off < 16; off <<= 1) {
                    s += __shfl_xor(s, off, 64);
                    d += __shfl_xor(d, off, 64);
                }
                const int row = brow + wm + i * 16 + quad * 4 + r;
                if (l16 == 0 && row < M) {
                    aS[row] = s;
                    aD[row] = d;
                }
            }
        }
    }
}

// ------- layer-1 gather: head-split (XCD-pinned), 16 nodes per wave ------
// head = blockIdx&7. Wave = 16 node-slots x 4 lanes (cl). nt bucket loads
// + nt output stores protect the L2-resident h slab.
__global__ __launch_bounds__(256) void gather1_kernel(
        const int* __restrict__ cursor, const int* __restrict__ bucket,
        const float* __restrict__ a_src, const float* __restrict__ a_dst,
        const unsigned short* __restrict__ h1hm, const float* __restrict__ b1,
        unsigned short* __restrict__ out1b, int Nn) {
    const int h = blockIdx.x & 7;
    const int lane = threadIdx.x & 63;
    const int wv = threadIdx.x >> 6;
    const int sub = lane >> 2;           // node slot 0..15
    const int cl  = lane & 3;            // channel group, c = cl*8
    const int d = (blockIdx.x >> 3) * 64 + wv * 16 + sub;
    if (d >= Nn) return;

    const unsigned short* hh = h1hm + (size_t)h * Nn * HID;
    const float* asrc = a_src + (size_t)h * Nn;
    const float adst = a_dst[(size_t)h * Nn + d];

    float denom, acc[8];
    {   // self-loop
        const float w = __expf(leaky(asrc[d] + adst));
        const u16x8 v = *(const u16x8*)&hh[(size_t)d * HID + cl * 8];
        denom = w;
#pragma unroll
        for (int q = 0; q < 8; ++q) acc[q] = w * b2f(v[q]);
    }
    const int base = d * CAP;
    const int cnt = min(cursor[d], CAP);
    for (int i = 0; i < cnt; i += 4) {
        const i32x4 s4 =
            __builtin_nontemporal_load((const i32x4*)&bucket[base + i]);
        int s[4];
        bool ok[4];
#pragma unroll
        for (int j = 0; j < 4; ++j) {
            ok[j] = (i + j) < cnt;
            s[j] = ok[j] ? s4[j] : d;
        }
        float e[4];
#pragma unroll
        for (int j = 0; j < 4; ++j) e[j] = asrc[s[j]];
        u16x8 vv[4];
#pragma unroll
        for (int j = 0; j < 4; ++j)
            vv[j] = *(const u16x8*)&hh[(size_t)s[j] * HID + cl * 8];
#pragma unroll
        for (int j = 0; j < 4; ++j) {
            float w = __expf(leaky(e[j] + adst));
            w = ok[j] ? w : 0.f;
            denom += w;
#pragma unroll
            for (int q = 0; q < 8; ++q) acc[q] += w * b2f(vv[j][q]);
        }
    }
    const float inv = 1.f / denom;
    const int c = h * HID + cl * 8;
    u16x8 o;
#pragma unroll
    for (int q = 0; q < 8; ++q)
        o[q] = f2b(fmaxf(acc[q] * inv + b1[c + q], 0.f));
    __builtin_nontemporal_store(o, (u16x8*)&out1b[(size_t)d * F1 + c]);
}

// ---------------- layer-2 gather: 4 nodes/wave x 16 lanes x 8B ----------
__global__ __launch_bounds__(256) void gather2_kernel(
        const int* __restrict__ cursor, const int* __restrict__ bucket,
        const float* __restrict__ a_src, const float* __restrict__ a_dst,
        const unsigned short* __restrict__ h2b, const float* __restrict__ b2,
        float* __restrict__ out, int Nn) {
    const int lane = threadIdx.x & 63;
    const int sub  = lane >> 4;          // which of 4 nodes in the wave
    const int l    = lane & 15;
    int d = blockIdx.x * 16 + (threadIdx.x >> 6) * 4 + sub;
    const bool valid = d < Nn;
    if (!valid) d = Nn - 1;
    const int c = l * 4;

    const float adst = a_dst[d];
    float a0, a1, a2, a3, denom;
    {   // self-loop
        const float w = __expf(leaky(a_src[d] + adst));
        const ushort4 v = *(const ushort4*)&h2b[(size_t)d * F2 + c];
        denom = w;
        a0 = w * b2f(v.x); a1 = w * b2f(v.y);
        a2 = w * b2f(v.z); a3 = w * b2f(v.w);
    }
    const int base = d * CAP;
    const int cnt = min(cursor[d], CAP);
    for (int i = 0; i < cnt; i += 4) {
        const i32x4 s4 =
            __builtin_nontemporal_load((const i32x4*)&bucket[base + i]);
        float e[4];
        ushort4 vv[4];
        bool ok[4];
#pragma unroll
        for (int jj = 0; jj < 4; ++jj) {
            ok[jj] = (i + jj) < cnt;
            const int ss = ok[jj] ? s4[jj] : d;
            e[jj] = a_src[ss];
            vv[jj] = *(const ushort4*)&h2b[(size_t)ss * F2 + c];
        }
#pragma unroll
        for (int jj = 0; jj < 4; ++jj) {
            float w = __expf(leaky(e[jj] + adst));
            w = ok[jj] ? w : 0.f;
            denom += w;
            a0 += w * b2f(vv[jj].x); a1 += w * b2f(vv[jj].y);
            a2 += w * b2f(vv[jj].z); a3 += w * b2f(vv[jj].w);
        }
    }
    if (valid) {
        const float inv = 1.f / denom;
        f32x4 o;
        o[0] = a0 * inv + b2[c + 0];
        o[1] = a1 * inv + b2[c + 1];
        o[2] = a2 * inv + b2[c + 2];
        o[3] = a3 * inv + b2[c + 3];
        __builtin_nontemporal_store(o, (f32x4*)&out[(size_t)d * F2 + c]);
    }
}

extern "C" void kernel_launch(void* const* d_in, const int* in_sizes, int n_in,
                              void* d_out, int out_size, void* d_ws, size_t ws_size,
                              hipStream_t stream) {
    const float* x        = (const float*)d_in[0];
    const int*   ei       = (const int*)d_in[1];     // [2, E]
    const float* W1       = (const float*)d_in[2];   // [256,256]
    const float* att_src1 = (const float*)d_in[3];   // [8,32]
    const float* att_dst1 = (const float*)d_in[4];
    const float* b1       = (const float*)d_in[5];   // [256]
    const float* W2       = (const float*)d_in[6];   // [256,64]
    const float* att_src2 = (const float*)d_in[7];   // [1,64]
    const float* att_dst2 = (const float*)d_in[8];
    const float* b2       = (const float*)d_in[9];   // [64]
    float* out = (float*)d_out;                      // [N,64]

    const int Nn = in_sizes[0] / F1;    // 50000
    const int E  = in_sizes[1] / 2;     // 800000

    // workspace layout — wide-aligned arrays first
    char* p = (char*)d_ws;
    unsigned short* h1hm  = (unsigned short*)p; p += (size_t)Nn * F1 * 2; // [8][Nn][32]
    unsigned short* out1b = (unsigned short*)p; p += (size_t)Nn * F1 * 2;
    unsigned short* W1T   = (unsigned short*)p; p += (size_t)F1 * F1 * 2;
    unsigned short* W2T   = (unsigned short*)p; p += (size_t)F2 * F1 * 2;
    unsigned short* h2b   = (unsigned short*)p; p += (size_t)Nn * F2 * 2;
    float* a_src1 = (float*)p; p += (size_t)Nn * HEADS * 4;    // [8][Nn]
    float* a_dst1 = (float*)p; p += (size_t)Nn * HEADS * 4;    // [8][Nn]
    float* a_src2 = (float*)p; p += (size_t)Nn * 4;
    float* a_dst2 = (float*)p; p += (size_t)Nn * 4;
    int* cursor  = (int*)p; p += (size_t)Nn * 4;
    int* bucket  = (int*)p; p += (size_t)Nn * CAP * 4;         // 25.6 MB

    // --- setup: weight casts + cursor zero ---
    {
        const int total = F1 * F1 + F1 * F2 + Nn;
        setup_kernel<<<(total + 255) / 256, 256, 0, stream>>>(
            W1, W2, W1T, W2T, cursor, Nn);
    }
    // --- bucket scatter (by dst) ---
    scatter_kernel<<<(E + 255) / 256, 256, 0, stream>>>(ei, E, cursor, bucket);

    // --- layer 1: GEMM (+ fused att1) ---
    {
        dim3 grid((Nn + 127) / 128, F1 / 128);
        mfma_gemm<128, true, 2, 1><<<grid, 256, 0, stream>>>(
            x, W1T, h1hm, att_src1, att_dst1, a_src1, a_dst1, Nn, F1, F1);
    }
    gather1_kernel<<<((Nn + 63) / 64) * 8, 256, 0, stream>>>(
        cursor, bucket, a_src1, a_dst1, h1hm, b1, out1b, Nn);

    // --- layer 2: GEMM (+ fused att2) ---
    {
        dim3 grid((Nn + 127) / 128, F2 / 64);
        mfma_gemm<64, false, 1, 2><<<grid, 256, 0, stream>>>(
            out1b, W2T, h2b, att_src2, att_dst2, a_src2, a_dst2, Nn, F2, F1);
    }
    gather2_kernel<<<(Nn + 15) / 16, 256, 0, stream>>>(
        cursor, bucket, a_src2, a_dst2, h2b, b2, out, Nn);
}